// Round 5
// baseline (66.485 us; speedup 1.0000x reference)
//
#include <hip/hip_runtime.h>

// Problem constants (from reference): B=16, L=4096, D=1024, K=64
#define Bn 16
#define Ln 4096
#define Dn 1024
#define Kn 64
#define CH 8                   // tokens per fine chunk (slot granularity)
#define SEGTOK 128             // tokens per segment (one stream block)
#define CPS (SEGTOK / CH)      // 16 chunks per segment
#define NSEG (Ln / SEGTOK)     // 32 segments per batch row
#define SLOTS (CPS + 1)        // 17 slots: exclusive prefix at chunk j, slot 16 = seg total
#define NSPAN (2 * Bn * Kn)    // 2048 span ints

static __device__ __forceinline__ void acc4(float4& a, const float4 v) {
    a.x += v.x; a.y += v.y; a.z += v.z; a.w += v.w;
}
static __device__ __forceinline__ void sub4(float4& a, const float4 v) {
    a.x -= v.x; a.y -= v.y; a.z -= v.z; a.w -= v.w;
}
static __device__ __forceinline__ void acc4w(float4& a, const float4 v, float w) {
    a.x += v.x * w; a.y += v.y * w; a.z += v.z * w; a.w += v.w * w;
}

// ---------------------------------------------------------------------------
// K1 (fused stream + scan): grid = B*NSEG segment blocks + B am-prefix
// blocks + 1 decode block.
//  - segment blocks: stream 128 token rows (512 KB) of one (b,seg) while
//    maintaining a running weighted sum; write the exclusive intra-segment
//    prefix at every 8-token chunk boundary (slots 0..15) + seg total
//    (slot 16). token_hidden is read exactly once; no separate scan pass.
//  - am-prefix blocks: exclusive token prefix of attention_mask per batch.
//  - decode block: canonicalize sent_spans to int32 (int64 layout detect).
// ---------------------------------------------------------------------------
__global__ __launch_bounds__(256) void fused_stage1_kernel(
    const float* __restrict__ x, const int* __restrict__ am,
    const unsigned int* __restrict__ spans_raw,
    float* __restrict__ Pf, int* __restrict__ Pam, int* __restrict__ dec) {
    const int bc = blockIdx.x;

    if (bc < Bn * NSEG) {
        // ---- segment stream + intra-segment prefix ----
        const int b = bc / NSEG;
        const int seg = bc % NSEG;
        const int d0 = threadIdx.x * 4;

        const float* xp = x + ((size_t)b * Ln + (size_t)seg * SEGTOK) * Dn + d0;
        const int* amp = am + b * Ln + seg * SEGTOK;
        float* pf = Pf + (size_t)bc * SLOTS * Dn + d0;

        float4 acc = {0.f, 0.f, 0.f, 0.f};
        for (int j = 0; j < CPS; ++j) {
            *(float4*)(pf + (size_t)j * Dn) = acc;   // exclusive prefix slot j
#pragma unroll
            for (int t = 0; t < CH; ++t) {
                const int l = j * CH + t;
                const float w = (float)amp[l];
                const float4 v = *(const float4*)(xp + (size_t)l * Dn);
                acc4w(acc, v, w);
            }
        }
        *(float4*)(pf + (size_t)CPS * Dn) = acc;     // segment total
    } else if (bc < Bn * NSEG + Bn) {
        // ---- am token-prefix for batch b ----
        const int b = bc - Bn * NSEG;
        const int t = threadIdx.x;
        const int i0 = t * 16;
        const int* amb = am + (size_t)b * Ln;
        int loc[16];
        int lsum = 0;
#pragma unroll
        for (int j = 0; j < 16; ++j) { loc[j] = amb[i0 + j]; lsum += loc[j]; }

        __shared__ int ssum[256];
        ssum[t] = lsum;
        __syncthreads();
        for (int off = 1; off < 256; off <<= 1) {
            int v = (t >= off) ? ssum[t - off] : 0;
            __syncthreads();
            ssum[t] += v;
            __syncthreads();
        }
        int run = ssum[t] - lsum;                    // exclusive offset
        int* pam = Pam + (size_t)b * (Ln + 1);
#pragma unroll
        for (int j = 0; j < 16; ++j) { pam[i0 + j] = run; run += loc[j]; }
        if (t == 255) pam[Ln] = run;
    } else {
        // ---- span decode ----
        __shared__ unsigned int sred[256];
        unsigned int acc = 0;
        for (int i = threadIdx.x; i < NSPAN / 2; i += 256)
            acc |= spans_raw[2 * i + 1];
        sred[threadIdx.x] = acc;
        __syncthreads();
        for (int off = 128; off > 0; off >>= 1) {
            if ((int)threadIdx.x < off) sred[threadIdx.x] |= sred[threadIdx.x + off];
            __syncthreads();
        }
        const bool is64 = (sred[0] == 0u);
        for (int i = threadIdx.x; i < NSPAN; i += 256)
            dec[i] = is64 ? (int)spans_raw[2 * i] : (int)spans_raw[i];
    }
}

// ---------------------------------------------------------------------------
// K2: per-span pooling. grid = B*K blocks, 256 threads, no syncthreads.
// mask_sum = Pam[e]-Pam[s]. use_am interior: intra-seg prefix diffs +
// middle segment totals (<=32 float4 loads, L2-resident Pf) + weighted
// edge rows (<=7 per side) from x. !use_am (rare): direct plain-mean loop.
// ---------------------------------------------------------------------------
__global__ __launch_bounds__(256) void span_pool_kernel(
    const float* __restrict__ x, const int* __restrict__ am,
    const int* __restrict__ spans, const float* __restrict__ Pf,
    const int* __restrict__ Pam, float* __restrict__ H,
    float* __restrict__ sent_mask) {
    const int bk = blockIdx.x;          // b*K + k
    const int b = bk / Kn;

    int s = spans[2 * bk];
    int e = spans[2 * bk + 1];
    if (s < 0) s = 0; if (s > Ln) s = Ln;
    if (e < 0) e = 0; if (e > Ln) e = Ln;
    const int len = (e > s) ? (e - s) : 0;
    if (e < s) e = s;

    const int* pam = Pam + (size_t)b * (Ln + 1);
    const int msum = pam[e] - pam[s];
    const bool use_am = (msum > 0);
    const bool valid = (len > 0);

    const int d0 = threadIdx.x * 4;
    const float* xb = x + (size_t)b * Ln * Dn + d0;
    const int* amb = am + (size_t)b * Ln;
    float4 acc = {0.f, 0.f, 0.f, 0.f};

    if (!use_am) {
        // rare: no attended tokens in span -> plain mean over [s,e)
        for (int l = s; l < e; ++l)
            acc4(acc, *(const float4*)(xb + (size_t)l * Dn));
    } else {
        // interior fine-chunk range [ca, cb); edges [s,e1hi) and [e2lo,e)
        const int ca = (s + CH - 1) / CH;
        const int cb = e / CH;
        int e1hi, e2lo, e2hi;
        if (ca <= cb) { e1hi = ca * CH; e2lo = cb * CH; e2hi = e; }
        else          { e1hi = e;       e2lo = 0;       e2hi = 0; }

        if (cb > ca) {
            const float* Pb = Pf + (size_t)b * NSEG * SLOTS * Dn + d0;
            const int sa = ca / CPS, ja = ca % CPS;
            const int sb = cb / CPS, jb = cb % CPS;
            if (sa == sb) {
                acc = *(const float4*)(Pb + (size_t)(sa * SLOTS + jb) * Dn);
                sub4(acc, *(const float4*)(Pb + (size_t)(sa * SLOTS + ja) * Dn));
            } else {
                // rest of segment sa
                acc = *(const float4*)(Pb + (size_t)(sa * SLOTS + CPS) * Dn);
                sub4(acc, *(const float4*)(Pb + (size_t)(sa * SLOTS + ja) * Dn));
                // full middle segments
                for (int ss = sa + 1; ss < sb; ++ss)
                    acc4(acc, *(const float4*)(Pb + (size_t)(ss * SLOTS + CPS) * Dn));
                // leading part of segment sb (sb may be NSEG only when jb==0)
                if (jb > 0)
                    acc4(acc, *(const float4*)(Pb + (size_t)(sb * SLOTS + jb) * Dn));
            }
        }

        for (int l = s; l < e1hi; ++l) {
            const float w = (float)amb[l];
            if (w != 0.f) acc4w(acc, *(const float4*)(xb + (size_t)l * Dn), w);
        }
        for (int l = e2lo; l < e2hi; ++l) {
            const float w = (float)amb[l];
            if (w != 0.f) acc4w(acc, *(const float4*)(xb + (size_t)l * Dn), w);
        }
    }

    const float denom = use_am ? (float)msum : (float)len;
    const float inv = valid ? (1.0f / denom) : 0.0f;
    float4 outv;
    outv.x = acc.x * inv; outv.y = acc.y * inv;
    outv.z = acc.z * inv; outv.w = acc.w * inv;

    *(float4*)(H + (size_t)bk * Dn + d0) = outv;
    if (threadIdx.x == 0) sent_mask[bk] = valid ? 1.0f : 0.0f;
}

extern "C" void kernel_launch(void* const* d_in, const int* in_sizes, int n_in,
                              void* d_out, int out_size, void* d_ws, size_t ws_size,
                              hipStream_t stream) {
    const float* x = (const float*)d_in[0];
    const int* am = (const int*)d_in[1];
    const unsigned int* spans_raw = (const unsigned int*)d_in[2];

    float* H = (float*)d_out;
    float* sent_mask = H + (size_t)Bn * Kn * Dn;

    // workspace layout: dec | Pam | Pf
    const size_t dec_bytes = NSPAN * sizeof(int);                  // 8 KB
    const size_t pam_bytes = (size_t)Bn * (Ln + 1) * sizeof(int);  // 262 KB
    int* dec = (int*)d_ws;
    int* Pam = (int*)((char*)d_ws + dec_bytes);
    float* Pf = (float*)((char*)d_ws + dec_bytes + pam_bytes);     // ~35.7 MB

    fused_stage1_kernel<<<Bn * NSEG + Bn + 1, 256, 0, stream>>>(
        x, am, spans_raw, Pf, Pam, dec);
    span_pool_kernel<<<Bn * Kn, 256, 0, stream>>>(
        x, am, dec, Pf, Pam, H, sent_mask);
}

// Round 6
// 48.504 us; speedup vs baseline: 1.3707x; 1.3707x over previous
//
#include <hip/hip_runtime.h>

// Problem constants (from reference): B=16, L=4096, D=1024, K=64
#define Bn 16
#define Ln 4096
#define Dn 1024
#define Kn 64
#define CH 16                  // tokens per fine chunk (slot granularity)
#define SEGTOK 128             // tokens per segment (one stream block)
#define CPS (SEGTOK / CH)      // 8 chunks per segment
#define NSEG (Ln / SEGTOK)     // 32 segments per batch row
#define SLOTS (CPS + 1)        // 9 slots: excl prefix at chunk j, slot 8 = seg total
#define NSPAN (2 * Bn * Kn)    // 2048 span ints

static __device__ __forceinline__ void acc4(float4& a, const float4 v) {
    a.x += v.x; a.y += v.y; a.z += v.z; a.w += v.w;
}
static __device__ __forceinline__ void sub4(float4& a, const float4 v) {
    a.x -= v.x; a.y -= v.y; a.z -= v.z; a.w -= v.w;
}
static __device__ __forceinline__ void acc4w(float4& a, const float4 v, float w) {
    a.x += v.x * w; a.y += v.y * w; a.z += v.z * w; a.w += v.w * w;
}

// ---------------------------------------------------------------------------
// K1 (fused stream + scan, zero-weight rows SKIPPED): grid = B*NSEG segment
// blocks + B am-prefix blocks + 1 decode block.
//  - segment blocks: stream the ATTENDED rows (am!=0, ~50%) of 128 tokens of
//    one (b,seg), maintaining a running weighted sum; write the exclusive
//    intra-segment prefix at every 16-token chunk boundary (slots 0..7) +
//    segment total (slot 8). Unattended rows contribute exactly 0 to the
//    weighted sum, so skipping their loads is bit-identical.
//  - am-prefix blocks: exclusive token prefix of attention_mask per batch.
//  - decode block: canonicalize sent_spans to int32 (int64 layout detect).
// ---------------------------------------------------------------------------
__global__ __launch_bounds__(256) void fused_stage1_kernel(
    const float* __restrict__ x, const int* __restrict__ am,
    const unsigned int* __restrict__ spans_raw,
    float* __restrict__ Pf, int* __restrict__ Pam, int* __restrict__ dec) {
    const int bc = blockIdx.x;

    if (bc < Bn * NSEG) {
        // ---- segment stream + intra-segment prefix, skipping w==0 rows ----
        const int b = bc / NSEG;
        const int seg = bc % NSEG;
        const int d0 = threadIdx.x * 4;

        const float* xp = x + ((size_t)b * Ln + (size_t)seg * SEGTOK) * Dn + d0;
        const int* amp = am + b * Ln + seg * SEGTOK;
        float* pf = Pf + (size_t)bc * SLOTS * Dn + d0;

        float4 acc = {0.f, 0.f, 0.f, 0.f};
        for (int j = 0; j < CPS; ++j) {
            *(float4*)(pf + (size_t)j * Dn) = acc;   // exclusive prefix slot j
            // thread-uniform am values -> scalar loads, wave-uniform branches
            int wv[CH];
#pragma unroll
            for (int t = 0; t < CH; ++t) wv[t] = amp[j * CH + t];
#pragma unroll
            for (int t = 0; t < CH; ++t) {
                if (wv[t] != 0) {
                    const int l = j * CH + t;
                    const float4 v = *(const float4*)(xp + (size_t)l * Dn);
                    acc4w(acc, v, (float)wv[t]);
                }
            }
        }
        *(float4*)(pf + (size_t)CPS * Dn) = acc;     // segment total
    } else if (bc < Bn * NSEG + Bn) {
        // ---- am token-prefix for batch b ----
        const int b = bc - Bn * NSEG;
        const int t = threadIdx.x;
        const int i0 = t * 16;
        const int* amb = am + (size_t)b * Ln;
        int loc[16];
        int lsum = 0;
#pragma unroll
        for (int j = 0; j < 16; ++j) { loc[j] = amb[i0 + j]; lsum += loc[j]; }

        __shared__ int ssum[256];
        ssum[t] = lsum;
        __syncthreads();
        for (int off = 1; off < 256; off <<= 1) {
            int v = (t >= off) ? ssum[t - off] : 0;
            __syncthreads();
            ssum[t] += v;
            __syncthreads();
        }
        int run = ssum[t] - lsum;                    // exclusive offset
        int* pam = Pam + (size_t)b * (Ln + 1);
#pragma unroll
        for (int j = 0; j < 16; ++j) { pam[i0 + j] = run; run += loc[j]; }
        if (t == 255) pam[Ln] = run;
    } else {
        // ---- span decode ----
        __shared__ unsigned int sred[256];
        unsigned int acc = 0;
        for (int i = threadIdx.x; i < NSPAN / 2; i += 256)
            acc |= spans_raw[2 * i + 1];
        sred[threadIdx.x] = acc;
        __syncthreads();
        for (int off = 128; off > 0; off >>= 1) {
            if ((int)threadIdx.x < off) sred[threadIdx.x] |= sred[threadIdx.x + off];
            __syncthreads();
        }
        const bool is64 = (sred[0] == 0u);
        for (int i = threadIdx.x; i < NSPAN; i += 256)
            dec[i] = is64 ? (int)spans_raw[2 * i] : (int)spans_raw[i];
    }
}

// ---------------------------------------------------------------------------
// K2: per-span pooling. grid = B*K blocks, 256 threads, no syncthreads.
// mask_sum = Pam[e]-Pam[s]. use_am interior: intra-seg prefix diffs +
// middle segment totals (L2-resident Pf) + weighted ATTENDED edge rows
// from x. !use_am (rare, tiny spans only): direct plain-mean loop.
// ---------------------------------------------------------------------------
__global__ __launch_bounds__(256) void span_pool_kernel(
    const float* __restrict__ x, const int* __restrict__ am,
    const int* __restrict__ spans, const float* __restrict__ Pf,
    const int* __restrict__ Pam, float* __restrict__ H,
    float* __restrict__ sent_mask) {
    const int bk = blockIdx.x;          // b*K + k
    const int b = bk / Kn;

    int s = spans[2 * bk];
    int e = spans[2 * bk + 1];
    if (s < 0) s = 0; if (s > Ln) s = Ln;
    if (e < 0) e = 0; if (e > Ln) e = Ln;
    const int len = (e > s) ? (e - s) : 0;
    if (e < s) e = s;

    const int* pam = Pam + (size_t)b * (Ln + 1);
    const int msum = pam[e] - pam[s];
    const bool use_am = (msum > 0);
    const bool valid = (len > 0);

    const int d0 = threadIdx.x * 4;
    const float* xb = x + (size_t)b * Ln * Dn + d0;
    const int* amb = am + (size_t)b * Ln;
    float4 acc = {0.f, 0.f, 0.f, 0.f};

    if (!use_am) {
        // rare: no attended tokens in span -> plain mean over [s,e)
        for (int l = s; l < e; ++l)
            acc4(acc, *(const float4*)(xb + (size_t)l * Dn));
    } else {
        // interior fine-chunk range [ca, cb); edges [s,e1hi) and [e2lo,e)
        const int ca = (s + CH - 1) / CH;
        const int cb = e / CH;
        int e1hi, e2lo, e2hi;
        if (ca <= cb) { e1hi = ca * CH; e2lo = cb * CH; e2hi = e; }
        else          { e1hi = e;       e2lo = 0;       e2hi = 0; }

        if (cb > ca) {
            const float* Pb = Pf + (size_t)b * NSEG * SLOTS * Dn + d0;
            const int sa = ca / CPS, ja = ca % CPS;
            const int sb = cb / CPS, jb = cb % CPS;
            if (sa == sb) {
                acc = *(const float4*)(Pb + (size_t)(sa * SLOTS + jb) * Dn);
                sub4(acc, *(const float4*)(Pb + (size_t)(sa * SLOTS + ja) * Dn));
            } else {
                // rest of segment sa
                acc = *(const float4*)(Pb + (size_t)(sa * SLOTS + CPS) * Dn);
                sub4(acc, *(const float4*)(Pb + (size_t)(sa * SLOTS + ja) * Dn));
                // full middle segments
                for (int ss = sa + 1; ss < sb; ++ss)
                    acc4(acc, *(const float4*)(Pb + (size_t)(ss * SLOTS + CPS) * Dn));
                // leading part of segment sb (sb==NSEG only when jb==0)
                if (jb > 0)
                    acc4(acc, *(const float4*)(Pb + (size_t)(sb * SLOTS + jb) * Dn));
            }
        }

        for (int l = s; l < e1hi; ++l) {
            const float w = (float)amb[l];
            if (w != 0.f) acc4w(acc, *(const float4*)(xb + (size_t)l * Dn), w);
        }
        for (int l = e2lo; l < e2hi; ++l) {
            const float w = (float)amb[l];
            if (w != 0.f) acc4w(acc, *(const float4*)(xb + (size_t)l * Dn), w);
        }
    }

    const float denom = use_am ? (float)msum : (float)len;
    const float inv = valid ? (1.0f / denom) : 0.0f;
    float4 outv;
    outv.x = acc.x * inv; outv.y = acc.y * inv;
    outv.z = acc.z * inv; outv.w = acc.w * inv;

    *(float4*)(H + (size_t)bk * Dn + d0) = outv;
    if (threadIdx.x == 0) sent_mask[bk] = valid ? 1.0f : 0.0f;
}

extern "C" void kernel_launch(void* const* d_in, const int* in_sizes, int n_in,
                              void* d_out, int out_size, void* d_ws, size_t ws_size,
                              hipStream_t stream) {
    const float* x = (const float*)d_in[0];
    const int* am = (const int*)d_in[1];
    const unsigned int* spans_raw = (const unsigned int*)d_in[2];

    float* H = (float*)d_out;
    float* sent_mask = H + (size_t)Bn * Kn * Dn;

    // workspace layout: dec | Pam | Pf
    const size_t dec_bytes = NSPAN * sizeof(int);                  // 8 KB
    const size_t pam_bytes = (size_t)Bn * (Ln + 1) * sizeof(int);  // 262 KB
    int* dec = (int*)d_ws;
    int* Pam = (int*)((char*)d_ws + dec_bytes);
    float* Pf = (float*)((char*)d_ws + dec_bytes + pam_bytes);     // ~18.9 MB

    fused_stage1_kernel<<<Bn * NSEG + Bn + 1, 256, 0, stream>>>(
        x, am, spans_raw, Pf, Pam, dec);
    span_pool_kernel<<<Bn * Kn, 256, 0, stream>>>(
        x, am, dec, Pf, Pam, H, sent_mask);
}